// Round 6
// baseline (1712.896 us; speedup 1.0000x reference)
//
#include <hip/hip_runtime.h>

// Problem constants (match reference)
#define BB   8
#define HH   8
#define NN   65536
#define DD   128
#define BDIM 64
#define KK   32
#define NBLK 512

// All inputs/outputs are float32 per the reference dtypes.

// Workspace layout (float units)
#define OFF_SIMW 0u                       // B*H*N = 4194304
#define OFF_SIMR (OFF_SIMW + 4194304u)    // 4194304
#define OFF_NWK  (OFF_SIMR + 4194304u)    // 8192
#define OFF_NRK  (OFF_NWK + 8192u)        // 8192
#define OFF_CV   (OFF_NRK + 8192u)        // 8192
#define OFF_WIDX (OFF_CV + 8192u)         // 2048 (int)
#define OFF_WVAL (OFF_WIDX + 2048u)       // 2048
#define OFF_RIDX (OFF_WVAL + 2048u)       // 2048 (int)
#define OFF_RVAL (OFF_RIDX + 2048u)       // 2048
#define OFF_M2U  (OFF_RVAL + 2048u)       // B*256*D = 262144
#define OFF_RPH  (OFF_M2U + 262144u)      // 8192
#define OFF_CANDW (OFF_RPH + 8192u)       // 64*2048 u64 = 262144 floats
#define OFF_CANDR (OFF_CANDW + 262144u)   // 262144 floats
#define OFF_BAR  (OFF_CANDR + 262144u)    // 4 u32: cnt, gen

struct MegaArgs {
  const float *mem, *rkeys, *wkeys, *wvals, *erase, *adg, *beta_r, *beta_w,
              *W_b1, *b_b1, *W_b2, *b_b2, *W_merge, *b_merge, *ln_g, *ln_b, *decay;
  float *simw, *simr, *nwk, *nrk, *cvals;
  int *widx; float *wval; int *ridx; float *rval;
  float *m2u, *rph;
  unsigned long long *candw, *candr;
  unsigned *bar; float *out;
};

__device__ __forceinline__ unsigned ordf(float f) {
  unsigned u = __float_as_uint(f);
  return (u & 0x80000000u) ? ~u : (u | 0x80000000u);
}
__device__ __forceinline__ float unordf(unsigned u) {
  return (u & 0x80000000u) ? __uint_as_float(u & 0x7fffffffu) : __uint_as_float(~u);
}

// manual grid barrier: bar[0]=count, bar[1]=generation (zeroed by memset)
__device__ __forceinline__ void gsync(unsigned* bar) {
  __syncthreads();
  if (threadIdx.x == 0) {
    __threadfence();
    unsigned g = __hip_atomic_load(&bar[1], __ATOMIC_ACQUIRE, __HIP_MEMORY_SCOPE_AGENT);
    unsigned t = __hip_atomic_fetch_add(&bar[0], 1u, __ATOMIC_ACQ_REL, __HIP_MEMORY_SCOPE_AGENT);
    if (t == NBLK - 1) {
      __hip_atomic_store(&bar[0], 0u, __ATOMIC_RELAXED, __HIP_MEMORY_SCOPE_AGENT);
      __hip_atomic_fetch_add(&bar[1], 1u, __ATOMIC_RELEASE, __HIP_MEMORY_SCOPE_AGENT);
    } else {
      long spins = 0;
      while (__hip_atomic_load(&bar[1], __ATOMIC_ACQUIRE, __HIP_MEMORY_SCOPE_AGENT) == g) {
        __builtin_amdgcn_s_sleep(8);
        if (++spins > (1L << 22)) break;   // bailout: fail finite, never hang
      }
    }
    __threadfence();
  }
  __syncthreads();
}

// 256-thread sum; inactive threads must pass 0. sred4 = 4 floats LDS.
__device__ __forceinline__ float brsum256(float v, float* sred4, int tid) {
  #pragma unroll
  for (int o = 32; o > 0; o >>= 1) v += __shfl_xor(v, o);
  __syncthreads();
  if ((tid & 63) == 0) sred4[tid >> 6] = v;
  __syncthreads();
  float r = sred4[0] + sred4[1] + sred4[2] + sred4[3];
  __syncthreads();
  return r;
}

// stage1: exact per-wave top-32 of one 1024-elem span (verified R5 logic)
__device__ __forceinline__ void stage1_span(const float* __restrict__ sims,
                            unsigned long long* __restrict__ cand,
                            int vb, int tid, unsigned long long* sel) {
  int g = vb >> 4, chunk = vb & 15;
  int w = tid >> 6, lane = tid & 63;
  const float4* s4 = (const float4*)(sims + (size_t)g * NN + chunk * 4096 + w * 1024);
  unsigned long long keys[16];
  #pragma unroll
  for (int i = 0; i < 4; ++i) {
    float4 q = s4[i * 64 + lane];
    int base = chunk * 4096 + w * 1024 + (i * 64 + lane) * 4;
    float xs[4] = {q.x, q.y, q.z, q.w};
    #pragma unroll
    for (int e = 0; e < 4; ++e)
      keys[i * 4 + e] = ((unsigned long long)ordf(xs[e]) << 32)
                        | (unsigned)(~(unsigned)(base + e));
  }
  unsigned live = 0xFFFFu;
  for (int k = 0; k < KK; ++k) {
    unsigned long long lbest = 0ull; int lslot = -1;
    #pragma unroll
    for (int j = 0; j < 16; ++j)
      if (((live >> j) & 1u) && keys[j] > lbest) { lbest = keys[j]; lslot = j; }
    unsigned long long best = lbest;
    #pragma unroll
    for (int o = 32; o > 0; o >>= 1) {
      unsigned long long t = __shfl_xor(best, o);
      if (t > best) best = t;
    }
    if (lbest == best && lslot >= 0) live &= ~(1u << lslot);  // unique keys -> one owner
    if (lane == 0) sel[w * KK + k] = best;
  }
  __syncthreads();
  if (lane < KK)
    cand[(size_t)g * 2048 + (chunk * 4 + w) * KK + lane] = sel[w * KK + lane];
  __syncthreads();
}

// stage2: exact top-32 of 2048 candidates + softmax (verified R5 logic;
// run redundantly by all 4 waves; sel written by tid 0, outputs by tid<KK)
__device__ __forceinline__ void stage2_slice(const unsigned long long* __restrict__ cand,
                             int g, int* __restrict__ oidx, float* __restrict__ oval,
                             int tid, unsigned long long* sel) {
  int lane = tid & 63;
  unsigned long long keys[32];
  #pragma unroll
  for (int i = 0; i < 32; ++i) keys[i] = cand[(size_t)g * 2048 + i * 64 + lane];
  unsigned live = 0xFFFFFFFFu;
  for (int k = 0; k < KK; ++k) {
    unsigned long long lbest = 0ull; int lslot = -1;
    #pragma unroll
    for (int j = 0; j < 32; ++j)
      if (((live >> j) & 1u) && keys[j] > lbest) { lbest = keys[j]; lslot = j; }
    unsigned long long best = lbest;
    #pragma unroll
    for (int o = 32; o > 0; o >>= 1) {
      unsigned long long t = __shfl_xor(best, o);
      if (t > best) best = t;
    }
    if (lbest == best && lslot >= 0) live &= ~(1u << lslot);
    if (tid == 0) sel[k] = best;
  }
  __syncthreads();
  if (tid < KK) {
    unsigned long long kk = sel[tid];
    float v  = unordf((unsigned)(kk >> 32));
    int idx  = (int)~(unsigned)(kk & 0xffffffffu);
    float m0 = unordf((unsigned)(sel[0] >> 32));   // sel descending -> [0] is max
    float e  = expf(v - m0);
    float ss = e;
    #pragma unroll
    for (int o = 16; o > 0; o >>= 1) ss += __shfl_xor(ss, o);
    oidx[g * KK + tid] = idx;
    oval[g * KK + tid] = e / ss;
  }
  __syncthreads();
}

__global__ __launch_bounds__(256, 2) void mega(MegaArgs A) {
  const int blk = blockIdx.x;      // 0..511
  const int tid = threadIdx.x;     // 0..255
  __shared__ __align__(16) unsigned char smem[4608];

  // ===== P0: setup (keys+beta, MLP cvals, zero rph) — blocks 0..63 ==========
  if (blk < BB * HH) {
    float* sred4 = (float*)smem;                // 16 B
    float* wv_s  = (float*)(smem + 16);         // 512 B
    float* hid   = (float*)(smem + 16 + 512);   // 256 B
    int g = blk, d = tid & 127;
    bool act = tid < 128;

    if (act) A.rph[g * DD + d] = 0.f;
    float wk = act ? A.wkeys[g * DD + d] : 0.f;
    float rk = act ? A.rkeys[g * DD + d] : 0.f;
    float wv = act ? A.wvals[g * DD + d] : 0.f;
    if (act) wv_s[d] = wv;

    float s = brsum256(wk * wk, sred4, tid);
    if (act) A.nwk[g * DD + d] = wk / fmaxf(sqrtf(s), 1e-12f) * A.beta_w[g];
    s = brsum256(rk * rk, sred4, tid);
    if (act) A.nrk[g * DD + d] = rk / fmaxf(sqrtf(s), 1e-12f) * A.beta_r[g];

    __syncthreads();
    if (tid < BDIM) {
      float a = A.b_b1[tid];
      #pragma unroll 4
      for (int dd = 0; dd < DD; ++dd) a += wv_s[dd] * A.W_b1[dd * BDIM + tid];
      hid[tid] = a * 0.5f * (1.f + erff(a * 0.70710678118654752f));  // exact gelu
    }
    __syncthreads();
    if (act) {
      float c = A.b_b2[d];
      #pragma unroll 4
      for (int j = 0; j < BDIM; ++j) c += hid[j] * A.W_b2[j * DD + d];
      A.cvals[g * DD + d] = c;
    }
  }
  gsync(A.bar);

  // ===== P1: sims pass over memory (verified R5 k2 logic, 4 chunks/block) ===
  {
    int b = blk >> 6;
    const float* kw = A.nwk + b * HH * DD;   // block-uniform -> scalar loads
    const float* kr = A.nrk + b * HH * DD;
    for (int r = 0; r < 4; ++r) {
      int chunk = blk * 4 + r;                       // chunk>>8 == b
      int n = ((chunk & 255) << 8) + tid;
      const float4* rowp = (const float4*)(A.mem + ((size_t)b * NN + n) * DD);
      float dw[HH] = {0,0,0,0,0,0,0,0};
      float dr[HH] = {0,0,0,0,0,0,0,0};
      float nw = 0.f, nr = 0.f;
      for (int g = 0; g < 4; ++g) {                  // 4 x 128B bursts
        float4 q[8];
        #pragma unroll
        for (int i = 0; i < 8; ++i) q[i] = rowp[g * 8 + i];
        #pragma unroll
        for (int i = 0; i < 8; ++i) {
          float xs[4] = {q[i].x, q[i].y, q[i].z, q[i].w};
          #pragma unroll
          for (int e = 0; e < 4; ++e) {
            float xv = xs[e];
            float xr = xv + 1e-8f;
            nw += xv * xv;
            nr += xr * xr;
            int d = g * 32 + i * 4 + e;
            #pragma unroll
            for (int h = 0; h < HH; ++h) {
              dw[h] += xv * kw[h * DD + d];
              dr[h] += xr * kr[h * DD + d];
            }
          }
        }
      }
      float riw = 1.f / fmaxf(sqrtf(nw), 1e-12f);
      float rir = 1.f / fmaxf(sqrtf(nr), 1e-12f);
      #pragma unroll
      for (int h = 0; h < HH; ++h) {
        A.simw[(size_t)(b * HH + h) * NN + n] = dw[h] * riw;
        A.simr[(size_t)(b * HH + h) * NN + n] = dr[h] * rir;
      }
    }
  }
  gsync(A.bar);

  // ===== P2: write top-k ====================================================
  {
    unsigned long long* sel = (unsigned long long*)smem;   // 1 KB
    stage1_span(A.simw, A.candw, blk * 2 + 0, tid, sel);
    stage1_span(A.simw, A.candw, blk * 2 + 1, tid, sel);
  }
  gsync(A.bar);
  if (blk < BB * HH)
    stage2_slice(A.candw, blk, A.widx, A.wval, tid, (unsigned long long*)smem);
  gsync(A.bar);

  // ===== P3: apply erase/add, store unit rows, patch simr (4 slots/block) ===
  {
    int b  = blk >> 6;
    int s0 = (blk & 63) * 4;
    int*   swi  = (int*)smem;                  // 1024 B
    float* swv  = (float*)(smem + 1024);       // 1024 B
    float* sred = (float*)(smem + 2048);       // 4*9 floats
    swi[tid] = A.widx[b * 256 + tid];
    swv[tid] = A.wval[b * 256 + tid];
    __syncthreads();

    int d = tid & 127;
    bool act = tid < 128;
    for (int q = 0; q < 4; ++q) {
      int sl = s0 + q;
      int n  = swi[sl];
      bool dup = false;
      for (int j = 0; j < sl; ++j) if (swi[j] == n) { dup = true; break; }  // uniform
      if (!dup) {
        float E = 0.f, addd = 0.f;
        #pragma unroll
        for (int h = 0; h < HH; ++h) {
          float er = A.erase[b * HH + h];
          float ag = A.adg[b * HH + h];
          float aw = 0.f;
          #pragma unroll 4
          for (int k = 0; k < KK; ++k) {
            int j = h * KK + k;
            if (swi[j] == n) { float wv = swv[j]; E += wv * er; aw += wv; }
          }
          addd += aw * ag * A.cvals[(b * HH + h) * DD + d];
        }
        float v = 0.f;
        if (act) {
          float mval = A.mem[((size_t)b * NN + n) * DD + d];
          v = mval * (1.f - E * 0.125f) + addd * 0.125f + 1e-8f;
        }
        // fused 9-value reduction: [0]=v^2, [1..8]=nrk_h[d]*v (0 for tid>=128)
        float r[9];
        r[0] = v * v;
        #pragma unroll
        for (int h = 0; h < HH; ++h)
          r[1 + h] = act ? A.nrk[(b * HH + h) * DD + d] * v : 0.f;
        #pragma unroll
        for (int o = 32; o > 0; o >>= 1) {
          #pragma unroll
          for (int i = 0; i < 9; ++i) r[i] += __shfl_xor(r[i], o);
        }
        if ((tid & 63) == 0) {
          int w = tid >> 6;
          #pragma unroll
          for (int i = 0; i < 9; ++i) sred[w * 9 + i] = r[i];
        }
        __syncthreads();
        float S    = sred[0] + sred[9] + sred[18] + sred[27];
        float rinv = 1.f / fmaxf(sqrtf(S), 1e-12f);
        if (act) A.m2u[(size_t)(b * 256 + sl) * DD + d] = v * rinv;
        if (tid < HH) {
          float p = sred[1 + tid] + sred[10 + tid] + sred[19 + tid] + sred[28 + tid];
          A.simr[(size_t)(b * HH + tid) * NN + n] = p * rinv;
        }
      }
      __syncthreads();
    }
  }
  gsync(A.bar);

  // ===== P4: read top-k (on patched simr) ===================================
  {
    unsigned long long* sel = (unsigned long long*)smem;
    stage1_span(A.simr, A.candr, blk * 2 + 0, tid, sel);
    stage1_span(A.simr, A.candr, blk * 2 + 1, tid, sel);
  }
  gsync(A.bar);
  if (blk < BB * HH)
    stage2_slice(A.candr, blk, A.ridx, A.rval, tid, (unsigned long long*)smem);
  gsync(A.bar);

  // ===== P5: gather read rows -> rph (4 reads/block) ========================
  {
    int b  = blk >> 6;
    int r0 = (blk & 63) * 4;
    int*   swi   = (int*)smem;             // 1024 B
    float* sred4 = (float*)(smem + 1024);  // 16 B
    swi[tid] = A.widx[b * 256 + tid];
    __syncthreads();

    int d = tid & 127;
    bool act = tid < 128;
    for (int q = 0; q < 4; ++q) {
      int rem = r0 + q;
      int n   = A.ridx[b * 256 + rem];
      float w = A.rval[b * 256 + rem];
      float sc = 1.f / (1.f + expf(-A.decay[n]));
      int slot = -1;
      for (int j = 0; j < 256; ++j) if (swi[j] == n) { slot = j; break; }  // uniform
      float u = 0.f;
      if (slot >= 0) {
        if (act) u = A.m2u[(size_t)(b * 256 + slot) * DD + d];
      } else {
        float v = act ? (A.mem[((size_t)b * NN + n) * DD + d] + 1e-8f) : 0.f;
        float S = brsum256(v * v, sred4, tid);
        u = v / fmaxf(sqrtf(S), 1e-12f);
      }
      int h = rem >> 5;
      if (act) atomicAdd(&A.rph[(b * HH + h) * DD + d], w * sc * u);
      __syncthreads();
    }
  }
  gsync(A.bar);

  // ===== P6: merge matvec + LayerNorm — blocks 0..7 =========================
  if (blk < BB) {
    int b = blk;
    int d = tid & 127;
    int p = tid >> 7;            // 0..1, 512 j's each
    float* acc_s = (float*)smem;             // 2*128 floats
    float* accf  = (float*)(smem + 1024);    // 128 floats
    float* stat  = (float*)(smem + 1536);    // mu, var

    float a = 0.f;
    int j0 = p * 512;
    #pragma unroll 4
    for (int j = j0; j < j0 + 512; ++j)
      a += A.rph[b * HH * DD + j] * A.W_merge[j * DD + d];
    acc_s[p * DD + d] = a;
    __syncthreads();
    if (tid < DD) accf[d] = A.b_merge[d] + acc_s[d] + acc_s[DD + d];
    __syncthreads();
    if (tid < 64) {
      float x0 = accf[tid], x1 = accf[tid + 64];
      float s1 = x0 + x1, s2 = x0 * x0 + x1 * x1;
      #pragma unroll
      for (int o = 32; o > 0; o >>= 1) { s1 += __shfl_xor(s1, o); s2 += __shfl_xor(s2, o); }
      if (tid == 0) { stat[0] = s1 * (1.f / DD); stat[1] = s2 * (1.f / DD) - stat[0] * stat[0]; }
    }
    __syncthreads();
    if (tid < DD)
      A.out[b * DD + d] = (accf[d] - stat[0]) * rsqrtf(stat[1] + 1e-5f) * A.ln_g[d] + A.ln_b[d];
  }
}

extern "C" void kernel_launch(void* const* d_in, const int* in_sizes, int n_in,
                              void* d_out, int out_size, void* d_ws, size_t ws_size,
                              hipStream_t stream) {
  float* ws = (float*)d_ws;        // needs ~38 MB

  MegaArgs A;
  A.mem     = (const float*)d_in[0];
  A.rkeys   = (const float*)d_in[1];
  A.wkeys   = (const float*)d_in[2];
  A.wvals   = (const float*)d_in[3];
  A.erase   = (const float*)d_in[4];
  A.adg     = (const float*)d_in[5];
  A.beta_r  = (const float*)d_in[6];
  A.beta_w  = (const float*)d_in[7];
  A.W_b1    = (const float*)d_in[8];
  A.b_b1    = (const float*)d_in[9];
  A.W_b2    = (const float*)d_in[10];
  A.b_b2    = (const float*)d_in[11];
  A.W_merge = (const float*)d_in[12];
  A.b_merge = (const float*)d_in[13];
  A.ln_g    = (const float*)d_in[14];
  A.ln_b    = (const float*)d_in[15];
  A.decay   = (const float*)d_in[16];
  A.simw    = ws + OFF_SIMW;
  A.simr    = ws + OFF_SIMR;
  A.nwk     = ws + OFF_NWK;
  A.nrk     = ws + OFF_NRK;
  A.cvals   = ws + OFF_CV;
  A.widx    = (int*)(ws + OFF_WIDX);
  A.wval    = ws + OFF_WVAL;
  A.ridx    = (int*)(ws + OFF_RIDX);
  A.rval    = ws + OFF_RVAL;
  A.m2u     = ws + OFF_M2U;
  A.rph     = ws + OFF_RPH;
  A.candw   = (unsigned long long*)(ws + OFF_CANDW);
  A.candr   = (unsigned long long*)(ws + OFF_CANDR);
  A.bar     = (unsigned*)(ws + OFF_BAR);
  A.out     = (float*)d_out;

  // zero the barrier state (workspace is poisoned 0xAA before every call)
  hipMemsetAsync((void*)A.bar, 0, 16, stream);
  hipLaunchKernelGGL(mega, dim3(NBLK), dim3(256), 0, stream, A);
}